// Round 23
// baseline (83.873 us; speedup 1.0000x reference)
//
#include <hip/hip_runtime.h>
#include <hip/hip_fp16.h>

#define BATCH 32
#define TLEN  4096
#define CH    128      // C == F == 128
#define KW    3
#define DIL   8

#define BM    64                 // output rows per block (3-block/CU build)
#define HROWS (BM + 2 * DIL)     // 80  h rows
#define XROWS (BM + 4 * DIL)     // 96  x rows
#define LDSC  132                // 264B stride ≡ 2 (mod 32 dwords): ~2-way free.
                                 // 136 (≡4) gave 8-way conflicts (r6-r11).

typedef _Float16 f16x8  __attribute__((ext_vector_type(8)));
typedef float    f32x4  __attribute__((ext_vector_type(4)));
typedef float    f32x16 __attribute__((ext_vector_type(16)));

// ---------------------------------------------------------------------------
// Prep: Wt[j][f][c] = (f16) W[c][j][f]
// ---------------------------------------------------------------------------
__global__ void prep_weights_kernel(const float* __restrict__ W1,
                                    const float* __restrict__ W2,
                                    _Float16* __restrict__ Wt1,
                                    _Float16* __restrict__ Wt2) {
    const int total = KW * CH * CH;
    int idx = blockIdx.x * 256 + threadIdx.x;
    if (idx >= 2 * total) return;
    const float* W  = (idx < total) ? W1 : W2;
    _Float16*    Wt = (idx < total) ? Wt1 : Wt2;
    int r = idx % total;
    int j = r / (CH * CH);
    int f = (r / CH) % CH;
    int c = r % CH;
    Wt[j * CH * CH + f * CH + c] = (_Float16)W[c * (KW * CH) + j * CH + f];
}

// ---------------------------------------------------------------------------
// Fused TemporalDeConvBlock — r20's EXACT code shape (32x32 MFMA, separate
// buffers, same load/store ordering: the only build the allocator kept lean,
// VGPR=116) at BM=64 -> LDS 46.5KB -> 3 blocks/CU. This is the confound-
// free block-diversity test: r21/r22's aliased-buffer attempts both
// inflated VGPR to 176-180 (acc1+addressing live across the alias barrier)
// and never reached 3 blocks.
// Layouts (m74/m101): A row=l&31,k=(l>>5)*8+e; B col=l&31 same k;
// D col=l&31, row=(r&3)+8*(r>>2)+4*(l>>5).
// 256 thr = 4 waves; wave w owns cols [32w,32w+32); K = 24 steps of 16.
// G1: 3 row-tiles (tile 2 partial: A-rows clamped at 95, h-store masks
// r>=8). G2: 2 row-tiles, A-rows <= 79 (in range).
// LESSONS: caps below live-set spill (r3/r5); 512-thr pinned to 64 VGPR
// (r4/r6/r7); alias-barrier inflates regs (r21/r22); LDSC mod-32 rule;
// WRITE~65MB = no-spill invariant; VGPR>=150 => test confounded.
// ---------------------------------------------------------------------------
__global__ __launch_bounds__(256)
void fused_deconv_kernel(const float* __restrict__ x,
                         const _Float16* __restrict__ Wt1,
                         const float* __restrict__ bias1,
                         const _Float16* __restrict__ Wt2,
                         const float* __restrict__ bias2,
                         float* __restrict__ out)
{
    __shared__ __align__(16) _Float16 xs[XROWS][LDSC];   // 96*264 = 25344 B
    __shared__ __align__(16) _Float16 hs[HROWS][LDSC];   // 80*264 = 21120 B

    const int tid  = threadIdx.x;
    const int lane = tid & 63;
    const int wid  = tid >> 6;         // 0..3
    const int l31  = lane & 31;
    const int hg   = lane >> 5;        // 0..1 (K half-group)
    const int hg8  = hg << 3;
    const int nc   = wid << 5;         // wave column base: 0,32,64,96

    // XCD-aware bijective swizzle: grid 2048 = 8 XCDs x 256 chunks.
    const int bt0 = blockIdx.x;
    const int bt  = (bt0 & 7) * 256 + (bt0 >> 3);
    const int b   = bt >> 6;           // 64 tiles per batch
    const int t0  = (bt & 63) << 6;

    // ---- GEMM1 weight fragments (r20 position; compiler sinks into loop)
    f16x8 w1[24];
#pragma unroll
    for (int s = 0; s < 24; ++s) {
        const int j  = s >> 3;
        const int cb = (s & 7) << 4;
        w1[s] = *(const f16x8*)(Wt1 + (size_t)j * (CH * CH)
                                + (nc + l31) * CH + cb + hg8);
    }

    // ---- stage x window (f32 -> f16), rows t0..t0+95, zero past TLEN.
#pragma unroll
    for (int p = 0; p < 6; ++p) {
        const int i   = tid + 256 * p;
        const int row = i >> 4;
        const int c8  = (i & 15) << 3;
        const int t   = t0 + row;
        f16x8 o;
        if (t < TLEN) {
            const float* xp = x + ((size_t)b * TLEN + t) * CH + c8;
            f32x4 v0 = *(const f32x4*)(xp + 0);
            f32x4 v1 = *(const f32x4*)(xp + 4);
            o[0] = (_Float16)v0[0]; o[1] = (_Float16)v0[1];
            o[2] = (_Float16)v0[2]; o[3] = (_Float16)v0[3];
            o[4] = (_Float16)v1[0]; o[5] = (_Float16)v1[1];
            o[6] = (_Float16)v1[2]; o[7] = (_Float16)v1[3];
        } else {
            o = (f16x8){};
        }
        *(f16x8*)&xs[row][c8] = o;
    }

    const float bv1 = 128.0f * bias1[nc + l31];
    const float bv2 = 128.0f * bias2[nc + l31];

    __syncthreads();   // barrier 1: xs published

    // ---- GEMM1: h rows 0..79 (3 row-tiles, tile 2 partial), cols
    // [nc,nc+32) — 72 MFMA / 72 ds_read per wave.
    f32x16 acc1[3];
#pragma unroll
    for (int rt = 0; rt < 3; ++rt) acc1[rt] = (f32x16){};
#pragma unroll
    for (int s = 0; s < 24; ++s) {
        const int j     = s >> 3;
        const int cb    = (s & 7) << 4;
        const int shift = (2 - j) * DIL;
#pragma unroll
        for (int rt = 0; rt < 3; ++rt) {
            int row = rt * 32 + l31 + shift;
            if (rt == 2) row = (row > 95) ? 95 : row;   // clamp garbage lanes
            f16x8 af = *(const f16x8*)&xs[row][cb + hg8];
            acc1[rt] = __builtin_amdgcn_mfma_f32_32x32x16_f16(af, w1[s], acc1[rt], 0, 0, 0);
        }
    }

    // ---- GEMM2 weight fragments (r20 position: between G1 and h-store)
    f16x8 w2[24];
#pragma unroll
    for (int s = 0; s < 24; ++s) {
        const int j  = s >> 3;
        const int cb = (s & 7) << 4;
        w2[s] = *(const f16x8*)(Wt2 + (size_t)j * (CH * CH)
                                + (nc + l31) * CH + cb + hg8);
    }

    // ---- h-store: D col = nc+l31, row = rt*32 + (r&3)+8*(r>>2)+4*hg
#pragma unroll
    for (int rt = 0; rt < 3; ++rt) {
#pragma unroll
        for (int r = 0; r < 16; ++r) {
            if (rt == 2 && r >= 8) continue;     // rows >=80 don't exist
            const int row = rt * 32 + (r & 3) + 8 * (r >> 2) + 4 * hg;
            const int u   = t0 + row;
            const int nv  = 1 + (u < TLEN - DIL) + (u < TLEN - 2 * DIL);
            float v = acc1[rt][r] + (float)nv * bv1;
            v = fmaxf(v, 0.0f);
            hs[row][nc + l31] = (u < TLEN) ? (_Float16)v : (_Float16)0.0f;
        }
    }
    __syncthreads();   // barrier 2: hs published

    // ---- GEMM2: out rows 0..63 (2 row-tiles), cols [nc,nc+32)
    // — 48 MFMA / 48 ds_read per wave; A-rows <= 79 (in range).
    f32x16 acc2[2];
#pragma unroll
    for (int rt = 0; rt < 2; ++rt) acc2[rt] = (f32x16){};
#pragma unroll
    for (int s = 0; s < 24; ++s) {
        const int j     = s >> 3;
        const int cb    = (s & 7) << 4;
        const int shift = (2 - j) * DIL;
#pragma unroll
        for (int rt = 0; rt < 2; ++rt) {
            const int row = rt * 32 + l31 + shift;
            f16x8 af = *(const f16x8*)&hs[row][cb + hg8];
            acc2[rt] = __builtin_amdgcn_mfma_f32_32x32x16_f16(af, w2[s], acc2[rt], 0, 0, 0);
        }
    }

    // ---- epilogue: bias2 + relu, + residual (f16 from live xs), relu, store
#pragma unroll
    for (int rt = 0; rt < 2; ++rt) {
#pragma unroll
        for (int r = 0; r < 16; ++r) {
            const int row = rt * 32 + (r & 3) + 8 * (r >> 2) + 4 * hg;
            const int t   = t0 + row;
            const int nv  = 1 + (t < TLEN - DIL) + (t < TLEN - 2 * DIL);
            float v = acc2[rt][r] + (float)nv * bv2;
            v = fmaxf(v, 0.0f);
            v = fmaxf(v + (float)xs[row][nc + l31], 0.0f);
            out[((size_t)b * TLEN + t) * CH + nc + l31] = v;
        }
    }
}

// ---------------------------------------------------------------------------
extern "C" void kernel_launch(void* const* d_in, const int* in_sizes, int n_in,
                              void* d_out, int out_size, void* d_ws, size_t ws_size,
                              hipStream_t stream) {
    const float* x  = (const float*)d_in[0];
    const float* W1 = (const float*)d_in[1];
    const float* b1 = (const float*)d_in[2];
    const float* W2 = (const float*)d_in[3];
    const float* b2 = (const float*)d_in[4];
    float* out = (float*)d_out;

    _Float16* Wt1 = (_Float16*)d_ws;
    _Float16* Wt2 = Wt1 + KW * CH * CH;

    prep_weights_kernel<<<(2 * KW * CH * CH + 255) / 256, 256, 0, stream>>>(W1, W2, Wt1, Wt2);

    const int grid = BATCH * (TLEN / BM);   // 2048 blocks (= 8 XCDs x 256)
    fused_deconv_kernel<<<grid, 256, 0, stream>>>(x, Wt1, b1, Wt2, b2, out);
}

// Round 24
// 64.842 us; speedup vs baseline: 1.2935x; 1.2935x over previous
//
#include <hip/hip_runtime.h>
#include <hip/hip_fp16.h>

#define BATCH 32
#define TLEN  4096
#define CH    128      // C == F == 128
#define KW    3
#define DIL   8

#define BM    128                // output rows per block
#define HR    (BM + 2 * DIL)     // 144  h rows needed
#define WROWS (BM + 4 * DIL)     // 160  x rows needed
#define LDSC  132                // 264B stride ≡ 2 (mod 32 dwords): ~2-way free.
                                 // 136 (≡4) gave 8-way conflicts (r6-r11).

typedef _Float16 f16x8  __attribute__((ext_vector_type(8)));
typedef float    f32x4  __attribute__((ext_vector_type(4)));
typedef float    f32x16 __attribute__((ext_vector_type(16)));

// ---------------------------------------------------------------------------
// Prep: Wt[j][f][c] = (f16) W[c][j][f]
// ---------------------------------------------------------------------------
__global__ void prep_weights_kernel(const float* __restrict__ W1,
                                    const float* __restrict__ W2,
                                    _Float16* __restrict__ Wt1,
                                    _Float16* __restrict__ Wt2) {
    const int total = KW * CH * CH;
    int idx = blockIdx.x * 256 + threadIdx.x;
    if (idx >= 2 * total) return;
    const float* W  = (idx < total) ? W1 : W2;
    _Float16*    Wt = (idx < total) ? Wt1 : Wt2;
    int r = idx % total;
    int j = r / (CH * CH);
    int f = (r / CH) % CH;
    int c = r % CH;
    Wt[j * CH * CH + f * CH + c] = (_Float16)W[c * (KW * CH) + j * CH + f];
}

// ---------------------------------------------------------------------------
// Fused TemporalDeConvBlock — FINAL (r20 verbatim, measured best: 64.8us).
// 32x32x16 MFMA, BM=128, separate xs/hs buffers (2 barriers), residual from
// live xs window (f16), XCD-aware bijective block swizzle (grid 1024=8*128).
// Layouts (m74/m101-verified): A row=l&31,k=(l>>5)*8+e; B col=l&31 same k;
// D col=l&31, row=(r&3)+8*(r>>2)+4*(l>>5), r in [0,16).
// 256 thr = 4 waves; wave w owns cols [32w,32w+32). K = 3 taps x 128 c =
// 24 steps of 16. G1 row-tile 4 is partial: OOB A-rows clamped to 159,
// garbage masked at h-store (only regs r<8 -> rows 128..143).
//
// SESSION LEDGER (r0-r23): 116 -> 64.8us. Wins: layer fusion w/ halo (r1),
// reg-resident weights at lean footprint (r4), LDSC mod-32 bank rule (r12),
// XCD swizzle (r12), separate buffers + LDS residual (r14), 32x32 MFMA
// (r20). Individually falsified: occupancy/TLP (r11,r23), barrier count &
// semantics (r10,r14), bank conflicts (r12), L2 locality (r12), per-thread
// instr count (r13), reg-staged pipelining (r9/r10), ds_read ring prefetch
// (r15), DMA staging (r16), weight-load coalescing (r17), block-level phase
// diversity (r23). Ablations (r18/r19): stage ~5us, GEMM phases ~75% of
// wall at ~16% pipe busy — the plateau is the serial phase-latency
// structure of this short-K (384) fused op, not any single pipe.
// Spill traps: caps below live-set (r3/r5); 512-thr blocks pinned to 64
// VGPR (r4/r6/r7); alias barrier inflates live regs (r21/r22).
// ---------------------------------------------------------------------------
__global__ __launch_bounds__(256)
void fused_deconv_kernel(const float* __restrict__ x,
                         const _Float16* __restrict__ Wt1,
                         const float* __restrict__ bias1,
                         const _Float16* __restrict__ Wt2,
                         const float* __restrict__ bias2,
                         float* __restrict__ out)
{
    __shared__ __align__(16) _Float16 xs[WROWS][LDSC];   // 42240 B
    __shared__ __align__(16) _Float16 hs[HR][LDSC];      // 38016 B

    const int tid  = threadIdx.x;
    const int lane = tid & 63;
    const int wid  = tid >> 6;         // 0..3
    const int l31  = lane & 31;
    const int hg   = lane >> 5;        // 0..1 (K half-group)
    const int hg8  = hg << 3;
    const int nc   = wid << 5;         // wave column base: 0,32,64,96

    // XCD-aware bijective swizzle: grid 1024 = 8 XCDs x 128 chunks.
    const int bt0 = blockIdx.x;
    const int bt  = (bt0 & 7) * 128 + (bt0 >> 3);
    const int b   = bt >> 5;
    const int t0  = (bt & 31) << 7;

    // ---- GEMM1 weight fragments: 24 steps x 16B = 96 VGPRs (compiler
    // sinks these into the MFMA loop; measured VGPR=116 total).
    // B-frag: col f = nc + l31, k = cb + hg*8 + e.
    f16x8 w1[24];
#pragma unroll
    for (int s = 0; s < 24; ++s) {
        const int j  = s >> 3;
        const int cb = (s & 7) << 4;
        w1[s] = *(const f16x8*)(Wt1 + (size_t)j * (CH * CH)
                                + (nc + l31) * CH + cb + hg8);
    }

    // ---- stage x window (f32 -> f16), rows t0..t0+159, zero past TLEN.
#pragma unroll
    for (int p = 0; p < 10; ++p) {
        const int i   = tid + 256 * p;
        const int row = i >> 4;
        const int c8  = (i & 15) << 3;
        const int t   = t0 + row;
        f16x8 o;
        if (t < TLEN) {
            const float* xp = x + ((size_t)b * TLEN + t) * CH + c8;
            f32x4 v0 = *(const f32x4*)(xp + 0);
            f32x4 v1 = *(const f32x4*)(xp + 4);
            o[0] = (_Float16)v0[0]; o[1] = (_Float16)v0[1];
            o[2] = (_Float16)v0[2]; o[3] = (_Float16)v0[3];
            o[4] = (_Float16)v1[0]; o[5] = (_Float16)v1[1];
            o[6] = (_Float16)v1[2]; o[7] = (_Float16)v1[3];
        } else {
            o = (f16x8){};
        }
        *(f16x8*)&xs[row][c8] = o;
    }

    const float bv1 = 128.0f * bias1[nc + l31];   // per-lane scalar (col fixed)
    const float bv2 = 128.0f * bias2[nc + l31];

    __syncthreads();   // barrier 1: xs published

    // ---- GEMM1: h rows 0..143 (5 row-tiles of 32, tile 4 partial),
    // cols [nc,nc+32) — 120 MFMA / 120 ds_read per wave.
    f32x16 acc1[5];
#pragma unroll
    for (int rt = 0; rt < 5; ++rt) acc1[rt] = (f32x16){};
#pragma unroll
    for (int s = 0; s < 24; ++s) {
        const int j     = s >> 3;
        const int cb    = (s & 7) << 4;
        const int shift = (2 - j) * DIL;
#pragma unroll
        for (int rt = 0; rt < 5; ++rt) {
            int row = rt * 32 + l31 + shift;
            if (rt == 4) row = (row > 159) ? 159 : row;   // clamp garbage lanes
            f16x8 af = *(const f16x8*)&xs[row][cb + hg8];
            acc1[rt] = __builtin_amdgcn_mfma_f32_32x32x16_f16(af, w1[s], acc1[rt], 0, 0, 0);
        }
    }

    // ---- GEMM2 weight fragments (w1 dead, regs recycle)
    f16x8 w2[24];
#pragma unroll
    for (int s = 0; s < 24; ++s) {
        const int j  = s >> 3;
        const int cb = (s & 7) << 4;
        w2[s] = *(const f16x8*)(Wt2 + (size_t)j * (CH * CH)
                                + (nc + l31) * CH + cb + hg8);
    }

    // ---- h-store: D col = nc+l31, row = rt*32 + (r&3)+8*(r>>2)+4*hg
#pragma unroll
    for (int rt = 0; rt < 5; ++rt) {
#pragma unroll
        for (int r = 0; r < 16; ++r) {
            if (rt == 4 && r >= 8) continue;     // rows >=144 don't exist
            const int row = rt * 32 + (r & 3) + 8 * (r >> 2) + 4 * hg;
            const int u   = t0 + row;
            const int nv  = 1 + (u < TLEN - DIL) + (u < TLEN - 2 * DIL);
            float v = acc1[rt][r] + (float)nv * bv1;
            v = fmaxf(v, 0.0f);
            hs[row][nc + l31] = (u < TLEN) ? (_Float16)v : (_Float16)0.0f;
        }
    }
    __syncthreads();   // barrier 2: hs published

    // ---- GEMM2: out rows 0..127 (4 row-tiles), cols [nc,nc+32)
    // — 96 MFMA / 96 ds_read per wave. A-rows <= 96+31+16 = 143 (in range).
    f32x16 acc2[4];
#pragma unroll
    for (int rt = 0; rt < 4; ++rt) acc2[rt] = (f32x16){};
#pragma unroll
    for (int s = 0; s < 24; ++s) {
        const int j     = s >> 3;
        const int cb    = (s & 7) << 4;
        const int shift = (2 - j) * DIL;
#pragma unroll
        for (int rt = 0; rt < 4; ++rt) {
            const int row = rt * 32 + l31 + shift;
            f16x8 af = *(const f16x8*)&hs[row][cb + hg8];
            acc2[rt] = __builtin_amdgcn_mfma_f32_32x32x16_f16(af, w2[s], acc2[rt], 0, 0, 0);
        }
    }

    // ---- epilogue: bias2 + relu, + residual (f16 from live xs), relu, store
#pragma unroll
    for (int rt = 0; rt < 4; ++rt) {
#pragma unroll
        for (int r = 0; r < 16; ++r) {
            const int row = rt * 32 + (r & 3) + 8 * (r >> 2) + 4 * hg;
            const int t   = t0 + row;
            const int nv  = 1 + (t < TLEN - DIL) + (t < TLEN - 2 * DIL);
            float v = acc2[rt][r] + (float)nv * bv2;
            v = fmaxf(v, 0.0f);
            v = fmaxf(v + (float)xs[row][nc + l31], 0.0f);
            out[((size_t)b * TLEN + t) * CH + nc + l31] = v;
        }
    }
}

// ---------------------------------------------------------------------------
extern "C" void kernel_launch(void* const* d_in, const int* in_sizes, int n_in,
                              void* d_out, int out_size, void* d_ws, size_t ws_size,
                              hipStream_t stream) {
    const float* x  = (const float*)d_in[0];
    const float* W1 = (const float*)d_in[1];
    const float* b1 = (const float*)d_in[2];
    const float* W2 = (const float*)d_in[3];
    const float* b2 = (const float*)d_in[4];
    float* out = (float*)d_out;

    _Float16* Wt1 = (_Float16*)d_ws;
    _Float16* Wt2 = Wt1 + KW * CH * CH;

    prep_weights_kernel<<<(2 * KW * CH * CH + 255) / 256, 256, 0, stream>>>(W1, W2, Wt1, Wt2);

    const int grid = BATCH * (TLEN / BM);   // 1024 blocks (= 8 XCDs x 128)
    fused_deconv_kernel<<<grid, 256, 0, stream>>>(x, Wt1, b1, Wt2, b2, out);
}